// Round 3
// baseline (395.281 us; speedup 1.0000x reference)
//
#include <hip/hip_runtime.h>
#include <math.h>

#define BB 64
#define NN 8732
#define CC 81
#define TR 64                       // rows per tile
#define TPB 4                       // tiles per block (software pipeline depth)
#define CBX ((NN + TR * TPB - 1) / (TR * TPB))   // 35 blocks per batch, 256 rows each

// ---------------- init: zero per-b accumulators + output ----------------
__global__ void init_kernel(unsigned* acc, float* out) {
    int i = threadIdx.x;
    if (i < 4 * BB) acc[i] = 0u;   // num_pos[B], pos_sum[B], loc_cnt[B], loc_sum[B]
    if (i == 0) out[0] = 0.f;
}

__device__ __forceinline__ float4 ld4g(const float* __restrict__ p, size_t gf, size_t TOTF) {
    if (gf + 4 <= TOTF) return *(const float4*)(p + gf);
    float4 r; float* rp = (float*)&r;
    #pragma unroll
    for (int c = 0; c < 4; ++c) rp[c] = (gf + c < TOTF) ? p[gf + c] : 0.f;
    return r;
}

// ---------------- fused conf + loc (single pass over rows) ----------------
// Positivity is derived from gt_loc (any component nonzero), which the loc loss
// reads anyway as coalesced float4 -- this removes the 324B-strided scalar
// gt_conf[...,0] reads (559K scattered cache lines, ~71MB of line fetches).
__global__ __launch_bounds__(256) void fused_kernel(
        const float* __restrict__ pred_conf,
        const float* __restrict__ gt_conf,
        const float* __restrict__ pred_loc,
        const float* __restrict__ gt_loc,
        float* __restrict__ neg_loss,
        int* __restrict__ num_pos,
        float* __restrict__ pos_sum,
        float* __restrict__ loc_cnt,
        float* __restrict__ loc_sum) {
    const int b        = blockIdx.y;
    const int tid      = threadIdx.x;
    const int tile0    = blockIdx.x * TPB;
    const int blockRow0 = tile0 * TR;           // first of 256 rows owned by this block

    __shared__ __align__(16) float lbuf[TR * CC + 8];
    __shared__ unsigned char s_pos[TPB * TR];   // per-row positive flag
    __shared__ int   s_cnt;
    __shared__ float s_sum;
    __shared__ float ls_sum, ls_cnt;
    float4* l4 = (float4*)lbuf;

    const size_t TOTF = (size_t)BB * NN * CC;
    const int r = tid >> 2;
    const int h = tid & 3;

    if (tid == 0) { s_cnt = 0; s_sum = 0.f; ls_sum = 0.f; ls_cnt = 0.f; }

    // ---- prologue: issue conf tile-0 prefetch first (overlaps phase 0) ----
    float4 rv[6];
    int rowBn = blockRow0;
    int nrn   = min(TR, NN - rowBn);
    size_t a0n; int shn, t4n;
    {
        size_t seg = ((size_t)b * NN + rowBn) * CC;
        a0n = seg & ~(size_t)3; shn = (int)(seg - a0n);
        t4n = (shn + nrn * CC + 3) >> 2;
    }
    #pragma unroll
    for (int j = 0; j < 6; ++j) {
        int i = tid + 256 * j;
        if (i < t4n) rv[j] = ld4g(pred_conf, a0n + 4 * (size_t)i, TOTF);
    }

    // ---- phase 0: loc loss + positive detection, one row per thread ----
    {
        const int n = blockRow0 + tid;
        float sum = 0.f, cnt = 0.f;
        unsigned char pos = 0;
        if (n < NN) {
            size_t idx = (size_t)b * NN + n;
            float4 p = ((const float4*)pred_loc)[idx];
            float4 g = ((const float4*)gt_loc)[idx];
            float pv[4] = {p.x, p.y, p.z, p.w};
            float gv[4] = {g.x, g.y, g.z, g.w};
            #pragma unroll
            for (int c = 0; c < 4; ++c) {
                if (gv[c] != 0.f) {
                    pos = 1;
                    float d = fabsf(pv[c] - gv[c]);
                    sum += (d < 1.f) ? 0.5f * d * d : d - 0.5f;
                }
            }
            if (pos) cnt = 1.f;
        }
        s_pos[tid] = pos;
        for (int o = 32; o; o >>= 1) {
            sum += __shfl_down(sum, o, 64);
            cnt += __shfl_down(cnt, o, 64);
        }
        __syncthreads();               // ls_* init visible (and s_pos published)
        if ((tid & 63) == 0) { atomicAdd(&ls_sum, sum); atomicAdd(&ls_cnt, cnt); }
    }
    __syncthreads();                   // ls_* final; s_pos visible to all
    if (tid == 0) { atomicAdd(&loc_sum[b], ls_sum); atomicAdd(&loc_cnt[b], ls_cnt); }

    // ---- conf pipeline: prefetch AFTER barrier, compute current tile ----
    for (int t = 0; t < TPB; ++t) {
        const int   c_rowB = rowBn, c_nr = nrn, c_sh = shn, c_t4 = t4n;
        const int   c_loc  = c_rowB - blockRow0;
        if (c_rowB >= NN) break;                       // uniform

        __syncthreads();                               // LDS free (prev compute done)
        #pragma unroll
        for (int j = 0; j < 6; ++j) {                  // consumes rv (vmcnt wait here)
            int i = tid + 256 * j;
            if (i < c_t4) l4[i] = rv[j];
        }
        __syncthreads();                               // LDS ready

        // prefetch next tile: overlaps compute below
        const int nrowB = (tile0 + t + 1) * TR;
        if (t + 1 < TPB && nrowB < NN) {
            rowBn = nrowB; nrn = min(TR, NN - nrowB);
            size_t seg = ((size_t)b * NN + nrowB) * CC;
            a0n = seg & ~(size_t)3; shn = (int)(seg - a0n);
            t4n = (shn + nrn * CC + 3) >> 2;
            #pragma unroll
            for (int j = 0; j < 6; ++j) {
                int i = tid + 256 * j;
                if (i < t4n) rv[j] = ld4g(pred_conf, a0n + 4 * (size_t)i, TOTF);
            }
        } else {
            rowBn = NN;                                // sentinel -> break next iter
        }

        // ---- compute current tile: quad (4 threads) per row ----
        if (r < c_nr) {
            const int c0 = h * 20 + (h > 0 ? 1 : 0);
            const int nc = (h == 0) ? 21 : 20;
            const float* row = lbuf + c_sh + r * CC;
            const size_t gbase = ((size_t)b * NN + c_rowB + r) * CC;

            float v[21];
            #pragma unroll
            for (int j = 0; j < 21; ++j)
                v[j] = (j < nc) ? row[c0 + j] : -1e30f;

            float m = v[0];
            #pragma unroll
            for (int j = 1; j < 21; ++j) m = fmaxf(m, v[j]);
            m = fmaxf(m, __shfl_xor(m, 1, 64));
            m = fmaxf(m, __shfl_xor(m, 2, 64));

            float e = 0.f;
            #pragma unroll
            for (int j = 0; j < 21; ++j) e += __expf(v[j] - m);   // pad -> exp -> 0
            e += __shfl_xor(e, 1, 64);
            e += __shfl_xor(e, 2, 64);

            const bool pos = (s_pos[c_loc + r] != 0);  // LDS flag, no strided global
            float x_sel = v[0];                        // one-hot dot = v[0] for negatives
            if (pos) {
                float d = 0.f;
                #pragma unroll
                for (int j = 0; j < 21; ++j)
                    if (j < nc) d += gt_conf[gbase + c0 + j] * v[j];
                d += __shfl_xor(d, 1, 64);
                d += __shfl_xor(d, 2, 64);
                x_sel = d;                             // pred at one-hot label
            }

            const float loss = m + __logf(e) - x_sel;
            if (h == 0) {
                neg_loss[(size_t)b * NN + c_rowB + r] = pos ? 0.f : loss;
                if (pos) { atomicAdd(&s_cnt, 1); atomicAdd(&s_sum, loss); }
            }
        }
    }

    __syncthreads();
    if (tid == 0 && s_cnt) {
        atomicAdd(&num_pos[b], s_cnt);
        atomicAdd(&pos_sum[b], s_sum);
    }
}

// ---------------- per-batch radix select + finalize (atomic mean) ----------------
__global__ __launch_bounds__(256) void select_kernel(
        const float* __restrict__ neg_loss,
        const int*   __restrict__ num_pos,
        const float* __restrict__ pos_sum,
        const float* __restrict__ loc_cnt,
        const float* __restrict__ loc_sum,
        float* __restrict__ out) {
    const int b    = blockIdx.x;
    const int tid  = threadIdx.x;
    const int lane = tid & 63;
    __shared__ unsigned vals[NN];        // 34928 B
    __shared__ unsigned hist[256];
    __shared__ unsigned sh_prefix, sh_r;
    __shared__ float    s_part[4];

    // NN = 8732 = 2183 uint4 exactly -> vectorized load, no tail
    {
        const uint4* src = (const uint4*)(neg_loss + (size_t)b * NN);
        uint4* dst = (uint4*)vals;
        #pragma unroll 3
        for (int i = tid; i < NN / 4; i += 256)
            dst[i] = src[i];
    }

    const int np = num_pos[b];
    const int k  = min(3 * np, NN - 1);  // clip(int(num_neg), 0, N-1)
    if (tid == 0) { sh_prefix = 0u; sh_r = (unsigned)k; }
    __syncthreads();

    unsigned prefix_mask = 0u;
    for (int p = 3; p >= 0; --p) {
        const unsigned pref = sh_prefix;
        const unsigned r    = sh_r;
        hist[tid] = 0u;
        __syncthreads();

        // ballot-aggregated histogram: one atomic per distinct bin per wave
        for (int i0 = 0; i0 < NN; i0 += 256) {
            const int i = i0 + tid;
            const bool act = (i < NN) && ((vals[i] & prefix_mask) == pref);
            const unsigned v   = act ? vals[i] : 0u;
            const unsigned bin = (v >> (8 * p)) & 255u;
            unsigned long long mm = __ballot(act);
            #pragma unroll
            for (int bit = 0; bit < 8; ++bit) {
                unsigned long long s = __ballot(act && ((bin >> bit) & 1u));
                mm &= ((bin >> bit) & 1u) ? s : ~s;
            }
            if (act && ((mm & ((1ull << lane) - 1ull)) == 0ull))
                atomicAdd(&hist[bin], (unsigned)__popcll(mm));
        }
        __syncthreads();

        // wave-0 suffix scan over 256 bins (4 bins/lane) + bin pick
        if (tid < 64) {
            const unsigned h0 = hist[4 * tid + 0];
            const unsigned h1 = hist[4 * tid + 1];
            const unsigned h2 = hist[4 * tid + 2];
            const unsigned h3 = hist[4 * tid + 3];
            unsigned T = h0 + h1 + h2 + h3;
            #pragma unroll
            for (int off = 1; off < 64; off <<= 1) {
                unsigned t2 = __shfl_down(T, off, 64);
                if (tid + off < 64) T += t2;
            }
            unsigned Tn = __shfl_down(T, 1, 64);
            if (tid == 63) Tn = 0u;
            const unsigned S4 = Tn, S3 = S4 + h3, S2 = S3 + h2, S1 = S2 + h1, S0 = S1 + h0;
            int bin = -1; unsigned Slo = 0u;
            if      (S1 <= r && r < S0) { bin = 4 * tid + 0; Slo = S1; }
            else if (S2 <= r && r < S1) { bin = 4 * tid + 1; Slo = S2; }
            else if (S3 <= r && r < S2) { bin = 4 * tid + 2; Slo = S3; }
            else if (S4 <= r && r < S3) { bin = 4 * tid + 3; Slo = S4; }
            if (bin >= 0) {
                sh_r = r - Slo;
                sh_prefix = pref | ((unsigned)bin << (8 * p));
            }
        }
        __syncthreads();
        prefix_mask |= 0xFFu << (8 * p);
    }

    const float thresh = __uint_as_float(sh_prefix);   // exact (k+1)-th largest
    float s = 0.f;
    #pragma unroll 4
    for (int i = tid; i < NN; i += 256) {
        float v = __uint_as_float(vals[i]);
        if (v > thresh) s += v;                        // strict >, matches reference
    }
    for (int o = 32; o; o >>= 1) s += __shfl_down(s, o, 64);
    if (lane == 0) s_part[tid >> 6] = s;
    __syncthreads();
    if (tid == 0) {
        float neg_sum = s_part[0] + s_part[1] + s_part[2] + s_part[3];
        float npf = (float)np;
        float res = pos_sum[b] / npf + neg_sum / (3.0f * npf) + loc_sum[b] / loc_cnt[b];
        atomicAdd(out, res * (1.0f / BB));
    }
}

extern "C" void kernel_launch(void* const* d_in, const int* in_sizes, int n_in,
                              void* d_out, int out_size, void* d_ws, size_t ws_size,
                              hipStream_t stream) {
    const float* pred_conf = (const float*)d_in[0];
    const float* pred_loc  = (const float*)d_in[1];
    const float* gt_conf   = (const float*)d_in[2];
    const float* gt_loc    = (const float*)d_in[3];

    float* neg      = (float*)d_ws;                 // B*N floats
    int*   num_pos  = (int*)(neg + (size_t)BB * NN);
    float* pos_sum  = (float*)(num_pos + BB);
    float* loc_cnt  = pos_sum + BB;
    float* loc_sum  = loc_cnt + BB;

    init_kernel<<<1, 256, 0, stream>>>((unsigned*)num_pos, (float*)d_out);

    dim3 fgrid(CBX, BB);                            // 35 x 64 (loc folded into conf blocks)
    fused_kernel<<<fgrid, 256, 0, stream>>>(pred_conf, gt_conf, pred_loc, gt_loc,
                                            neg, num_pos, pos_sum, loc_cnt, loc_sum);

    select_kernel<<<BB, 256, 0, stream>>>(neg, num_pos, pos_sum, loc_cnt, loc_sum,
                                          (float*)d_out);
}

// Round 4
// 365.453 us; speedup vs baseline: 1.0816x; 1.0816x over previous
//
#include <hip/hip_runtime.h>
#include <math.h>

#define BB 64
#define NN 8732
#define CC 81
#define TR 64                       // rows per tile
#define TPB 4                       // tiles per block (software pipeline depth)
#define CBX ((NN + TR * TPB - 1) / (TR * TPB))   // 35 blocks per batch, 256 rows each

__device__ __forceinline__ float4 ld4g(const float* __restrict__ p, size_t gf, size_t TOTF) {
    if (gf + 4 <= TOTF) return *(const float4*)(p + gf);
    float4 r; float* rp = (float*)&r;
    #pragma unroll
    for (int c = 0; c < 4; ++c) rp[c] = (gf + c < TOTF) ? p[gf + c] : 0.f;
    return r;
}

// ---------------- fused conf + loc (single pass over rows) ----------------
// Positivity derived from gt_loc (any component nonzero) -- removes the
// 324B-strided gt_conf[...,0] stream. Per-block PARTIAL arrays (written
// unconditionally) replace zero-init + global atomics, killing init_kernel.
__global__ __launch_bounds__(256) void fused_kernel(
        const float* __restrict__ pred_conf,
        const float* __restrict__ gt_conf,
        const float* __restrict__ pred_loc,
        const float* __restrict__ gt_loc,
        float* __restrict__ neg_loss,
        int*   __restrict__ np_part,     // [BB][CBX]
        float* __restrict__ ps_part,     // [BB][CBX]
        float* __restrict__ lc_part,     // [BB][CBX]
        float* __restrict__ ls_part,     // [BB][CBX]
        float* __restrict__ out) {
    const int b         = blockIdx.y;
    const int bx        = blockIdx.x;
    const int tid       = threadIdx.x;
    const int tile0     = bx * TPB;
    const int blockRow0 = tile0 * TR;           // first of 256 rows owned by this block

    // zero the output once per launch; select runs after this kernel completes
    if (b == 0 && bx == 0 && tid == 0) out[0] = 0.f;

    __shared__ __align__(16) float lbuf[TR * CC + 8];
    __shared__ unsigned char s_pos[TPB * TR];   // per-row positive flag
    __shared__ int   s_cnt;
    __shared__ float s_sum;
    __shared__ float ls_sum, ls_cnt;
    float4* l4 = (float4*)lbuf;

    const size_t TOTF = (size_t)BB * NN * CC;
    const int r = tid >> 2;
    const int h = tid & 3;

    if (tid == 0) { s_cnt = 0; s_sum = 0.f; ls_sum = 0.f; ls_cnt = 0.f; }

    // ---- prologue: issue conf tile-0 prefetch first (overlaps phase 0) ----
    float4 rv[6];
    int rowBn = blockRow0;
    int nrn   = min(TR, NN - rowBn);
    size_t a0n; int shn, t4n;
    {
        size_t seg = ((size_t)b * NN + rowBn) * CC;
        a0n = seg & ~(size_t)3; shn = (int)(seg - a0n);
        t4n = (shn + nrn * CC + 3) >> 2;
    }
    #pragma unroll
    for (int j = 0; j < 6; ++j) {
        int i = tid + 256 * j;
        if (i < t4n) rv[j] = ld4g(pred_conf, a0n + 4 * (size_t)i, TOTF);
    }

    // ---- phase 0: loc loss + positive detection, one row per thread ----
    {
        const int n = blockRow0 + tid;
        float sum = 0.f, cnt = 0.f;
        unsigned char pos = 0;
        if (n < NN) {
            size_t idx = (size_t)b * NN + n;
            float4 p = ((const float4*)pred_loc)[idx];
            float4 g = ((const float4*)gt_loc)[idx];
            float pv[4] = {p.x, p.y, p.z, p.w};
            float gv[4] = {g.x, g.y, g.z, g.w};
            #pragma unroll
            for (int c = 0; c < 4; ++c) {
                if (gv[c] != 0.f) {
                    pos = 1;
                    float d = fabsf(pv[c] - gv[c]);
                    sum += (d < 1.f) ? 0.5f * d * d : d - 0.5f;
                }
            }
            if (pos) cnt = 1.f;
        }
        s_pos[tid] = pos;
        for (int o = 32; o; o >>= 1) {
            sum += __shfl_down(sum, o, 64);
            cnt += __shfl_down(cnt, o, 64);
        }
        __syncthreads();               // ls_* init visible (and s_pos published)
        if ((tid & 63) == 0) { atomicAdd(&ls_sum, sum); atomicAdd(&ls_cnt, cnt); }
    }
    __syncthreads();                   // ls_* final; s_pos visible to all
    if (tid == 0) { ls_part[b * CBX + bx] = ls_sum; lc_part[b * CBX + bx] = ls_cnt; }

    // ---- conf pipeline: prefetch AFTER barrier, compute current tile ----
    for (int t = 0; t < TPB; ++t) {
        const int   c_rowB = rowBn, c_nr = nrn, c_sh = shn, c_t4 = t4n;
        const int   c_loc  = c_rowB - blockRow0;
        if (c_rowB >= NN) break;                       // uniform

        __syncthreads();                               // LDS free (prev compute done)
        #pragma unroll
        for (int j = 0; j < 6; ++j) {                  // consumes rv (vmcnt wait here)
            int i = tid + 256 * j;
            if (i < c_t4) l4[i] = rv[j];
        }
        __syncthreads();                               // LDS ready

        // prefetch next tile: overlaps compute below
        const int nrowB = (tile0 + t + 1) * TR;
        if (t + 1 < TPB && nrowB < NN) {
            rowBn = nrowB; nrn = min(TR, NN - nrowB);
            size_t seg = ((size_t)b * NN + nrowB) * CC;
            a0n = seg & ~(size_t)3; shn = (int)(seg - a0n);
            t4n = (shn + nrn * CC + 3) >> 2;
            #pragma unroll
            for (int j = 0; j < 6; ++j) {
                int i = tid + 256 * j;
                if (i < t4n) rv[j] = ld4g(pred_conf, a0n + 4 * (size_t)i, TOTF);
            }
        } else {
            rowBn = NN;                                // sentinel -> break next iter
        }

        // ---- compute current tile: quad (4 threads) per row ----
        if (r < c_nr) {
            const int c0 = h * 20 + (h > 0 ? 1 : 0);
            const int nc = (h == 0) ? 21 : 20;
            const float* row = lbuf + c_sh + r * CC;
            const size_t gbase = ((size_t)b * NN + c_rowB + r) * CC;

            float v[21];
            #pragma unroll
            for (int j = 0; j < 21; ++j)
                v[j] = (j < nc) ? row[c0 + j] : -1e30f;

            float m = v[0];
            #pragma unroll
            for (int j = 1; j < 21; ++j) m = fmaxf(m, v[j]);
            m = fmaxf(m, __shfl_xor(m, 1, 64));
            m = fmaxf(m, __shfl_xor(m, 2, 64));

            float e = 0.f;
            #pragma unroll
            for (int j = 0; j < 21; ++j) e += __expf(v[j] - m);   // pad -> exp -> 0
            e += __shfl_xor(e, 1, 64);
            e += __shfl_xor(e, 2, 64);

            const bool pos = (s_pos[c_loc + r] != 0);  // LDS flag, no strided global
            float x_sel = v[0];                        // one-hot dot = v[0] for negatives
            if (pos) {
                float d = 0.f;
                #pragma unroll
                for (int j = 0; j < 21; ++j)
                    if (j < nc) d += gt_conf[gbase + c0 + j] * v[j];
                d += __shfl_xor(d, 1, 64);
                d += __shfl_xor(d, 2, 64);
                x_sel = d;                             // pred at one-hot label
            }

            const float loss = m + __logf(e) - x_sel;
            if (h == 0) {
                neg_loss[(size_t)b * NN + c_rowB + r] = pos ? 0.f : loss;
                if (pos) { atomicAdd(&s_cnt, 1); atomicAdd(&s_sum, loss); }
            }
        }
    }

    __syncthreads();
    if (tid == 0) {
        np_part[b * CBX + bx] = s_cnt;                 // unconditional: no zero-init needed
        ps_part[b * CBX + bx] = s_sum;
    }
}

// ---------------- per-batch radix select + finalize (atomic mean) ----------------
// 1024 threads: scan iterations per radix pass 35 -> 9.
__global__ __launch_bounds__(1024) void select_kernel(
        const float* __restrict__ neg_loss,
        const int*   __restrict__ np_part,
        const float* __restrict__ ps_part,
        const float* __restrict__ lc_part,
        const float* __restrict__ ls_part,
        float* __restrict__ out) {
    const int b    = blockIdx.x;
    const int tid  = threadIdx.x;
    const int lane = tid & 63;
    const int wv   = tid >> 6;           // 0..15
    __shared__ unsigned vals[NN];        // 34928 B
    __shared__ unsigned hist[256];
    __shared__ unsigned sh_prefix, sh_r;
    __shared__ float    s_red[16];
    __shared__ int      sh_np;
    __shared__ float    sh_ps, sh_lc, sh_ls;

    // NN = 8732 = 2183 uint4 exactly -> vectorized load, no tail
    {
        const uint4* src = (const uint4*)(neg_loss + (size_t)b * NN);
        uint4* dst = (uint4*)vals;
        for (int i = tid; i < NN / 4; i += 1024) dst[i] = src[i];
    }

    // wave 0: reduce the 35 per-block partials while other waves load vals
    if (wv == 0) {
        int   np = (lane < CBX) ? np_part[b * CBX + lane] : 0;
        float ps = (lane < CBX) ? ps_part[b * CBX + lane] : 0.f;
        float lc = (lane < CBX) ? lc_part[b * CBX + lane] : 0.f;
        float ls = (lane < CBX) ? ls_part[b * CBX + lane] : 0.f;
        #pragma unroll
        for (int o = 32; o; o >>= 1) {
            np += __shfl_down(np, o, 64);
            ps += __shfl_down(ps, o, 64);
            lc += __shfl_down(lc, o, 64);
            ls += __shfl_down(ls, o, 64);
        }
        if (lane == 0) {
            sh_np = np; sh_ps = ps; sh_lc = lc; sh_ls = ls;
            sh_prefix = 0u;
            sh_r = (unsigned)min(3 * np, NN - 1);   // clip(int(num_neg), 0, N-1)
        }
    }
    __syncthreads();

    unsigned prefix_mask = 0u;
    for (int p = 3; p >= 0; --p) {
        const unsigned pref = sh_prefix;
        const unsigned r    = sh_r;
        if (tid < 256) hist[tid] = 0u;
        __syncthreads();

        // ballot-aggregated histogram: one atomic per distinct bin per wave
        for (int i0 = 0; i0 < NN; i0 += 1024) {
            const int i = i0 + tid;
            const bool act = (i < NN) && ((vals[i] & prefix_mask) == pref);
            const unsigned v   = act ? vals[i] : 0u;
            const unsigned bin = (v >> (8 * p)) & 255u;
            unsigned long long mm = __ballot(act);
            #pragma unroll
            for (int bit = 0; bit < 8; ++bit) {
                unsigned long long s = __ballot(act && ((bin >> bit) & 1u));
                mm &= ((bin >> bit) & 1u) ? s : ~s;
            }
            if (act && ((mm & ((1ull << lane) - 1ull)) == 0ull))
                atomicAdd(&hist[bin], (unsigned)__popcll(mm));
        }
        __syncthreads();

        // wave-0 suffix scan over 256 bins (4 bins/lane) + bin pick
        if (tid < 64) {
            const unsigned h0 = hist[4 * tid + 0];
            const unsigned h1 = hist[4 * tid + 1];
            const unsigned h2 = hist[4 * tid + 2];
            const unsigned h3 = hist[4 * tid + 3];
            unsigned T = h0 + h1 + h2 + h3;
            #pragma unroll
            for (int off = 1; off < 64; off <<= 1) {
                unsigned t2 = __shfl_down(T, off, 64);
                if (tid + off < 64) T += t2;
            }
            unsigned Tn = __shfl_down(T, 1, 64);
            if (tid == 63) Tn = 0u;
            const unsigned S4 = Tn, S3 = S4 + h3, S2 = S3 + h2, S1 = S2 + h1, S0 = S1 + h0;
            int bin = -1; unsigned Slo = 0u;
            if      (S1 <= r && r < S0) { bin = 4 * tid + 0; Slo = S1; }
            else if (S2 <= r && r < S1) { bin = 4 * tid + 1; Slo = S2; }
            else if (S3 <= r && r < S2) { bin = 4 * tid + 2; Slo = S3; }
            else if (S4 <= r && r < S3) { bin = 4 * tid + 3; Slo = S4; }
            if (bin >= 0) {
                sh_r = r - Slo;
                sh_prefix = pref | ((unsigned)bin << (8 * p));
            }
        }
        __syncthreads();
        prefix_mask |= 0xFFu << (8 * p);
    }

    const float thresh = __uint_as_float(sh_prefix);   // exact (k+1)-th largest
    float s = 0.f;
    for (int i = tid; i < NN; i += 1024) {
        float v = __uint_as_float(vals[i]);
        if (v > thresh) s += v;                        // strict >, matches reference
    }
    #pragma unroll
    for (int o = 32; o; o >>= 1) s += __shfl_down(s, o, 64);
    if (lane == 0) s_red[wv] = s;
    __syncthreads();
    if (tid == 0) {
        float neg_sum = 0.f;
        #pragma unroll
        for (int w = 0; w < 16; ++w) neg_sum += s_red[w];
        float npf = (float)sh_np;
        float res = sh_ps / npf + neg_sum / (3.0f * npf) + sh_ls / sh_lc;
        atomicAdd(out, res * (1.0f / BB));
    }
}

extern "C" void kernel_launch(void* const* d_in, const int* in_sizes, int n_in,
                              void* d_out, int out_size, void* d_ws, size_t ws_size,
                              hipStream_t stream) {
    const float* pred_conf = (const float*)d_in[0];
    const float* pred_loc  = (const float*)d_in[1];
    const float* gt_conf   = (const float*)d_in[2];
    const float* gt_loc    = (const float*)d_in[3];

    float* neg     = (float*)d_ws;                  // B*N floats
    int*   np_part = (int*)(neg + (size_t)BB * NN); // [BB][CBX]
    float* ps_part = (float*)(np_part + BB * CBX);
    float* lc_part = ps_part + BB * CBX;
    float* ls_part = lc_part + BB * CBX;

    dim3 fgrid(CBX, BB);                            // 35 x 64
    fused_kernel<<<fgrid, 256, 0, stream>>>(pred_conf, gt_conf, pred_loc, gt_loc,
                                            neg, np_part, ps_part, lc_part, ls_part,
                                            (float*)d_out);

    select_kernel<<<BB, 1024, 0, stream>>>(neg, np_part, ps_part, lc_part, ls_part,
                                           (float*)d_out);
}

// Round 6
// 365.242 us; speedup vs baseline: 1.0822x; 1.0006x over previous
//
#include <hip/hip_runtime.h>
#include <math.h>

#define BB 64
#define NN 8732
#define CC 81
#define CBX ((NN + 255) / 256)      // 35 blocks per batch, 256 rows each

// ---------------- fused conf + loc, no LDS staging ----------------
// Each quad (4 threads) owns one row: thread h holds a private contiguous
// 21-float slice (h=0: cols 0..20, else 20 cols). Direct global loads =
// 21 independent dwords/thread (wave sweeps a contiguous 5.2KB window,
// each line fetched once, rest L1 hits). No per-tile barriers, no LDS
// pipeline, no vmcnt(0) drain -> pure streaming, 21-way MLP.
__global__ __launch_bounds__(256) void fused_kernel(
        const float* __restrict__ pred_conf,
        const float* __restrict__ gt_conf,
        const float* __restrict__ pred_loc,
        const float* __restrict__ gt_loc,
        float* __restrict__ neg_loss,
        int*   __restrict__ np_part,     // [BB][CBX]
        float* __restrict__ ps_part,     // [BB][CBX]
        float* __restrict__ lc_part,     // [BB][CBX]
        float* __restrict__ ls_part,     // [BB][CBX]
        float* __restrict__ out) {
    const int b         = blockIdx.y;
    const int bx        = blockIdx.x;
    const int tid       = threadIdx.x;
    const int blockRow0 = bx * 256;     // first of 256 rows owned by this block

    // zero the output once per launch; select runs after this kernel completes
    if (b == 0 && bx == 0 && tid == 0) out[0] = 0.f;

    __shared__ unsigned char s_pos[256];   // per-row positive flag
    __shared__ int   s_cnt;
    __shared__ float s_sum;
    __shared__ float ls_sum, ls_cnt;

    const int r = tid >> 2;
    const int h = tid & 3;

    if (tid == 0) { s_cnt = 0; s_sum = 0.f; ls_sum = 0.f; ls_cnt = 0.f; }

    // ---- phase 0: loc loss + positive detection, one row per thread ----
    {
        const int n = blockRow0 + tid;
        float sum = 0.f, cnt = 0.f;
        unsigned char pos = 0;
        if (n < NN) {
            size_t idx = (size_t)b * NN + n;
            float4 p = ((const float4*)pred_loc)[idx];
            float4 g = ((const float4*)gt_loc)[idx];
            float pv[4] = {p.x, p.y, p.z, p.w};
            float gv[4] = {g.x, g.y, g.z, g.w};
            #pragma unroll
            for (int c = 0; c < 4; ++c) {
                if (gv[c] != 0.f) {
                    pos = 1;
                    float d = fabsf(pv[c] - gv[c]);
                    sum += (d < 1.f) ? 0.5f * d * d : d - 0.5f;
                }
            }
            if (pos) cnt = 1.f;
        }
        s_pos[tid] = pos;
        for (int o = 32; o; o >>= 1) {
            sum += __shfl_down(sum, o, 64);
            cnt += __shfl_down(cnt, o, 64);
        }
        __syncthreads();               // s_* init visible; s_pos published
        if ((tid & 63) == 0) { atomicAdd(&ls_sum, sum); atomicAdd(&ls_cnt, cnt); }
    }
    __syncthreads();                   // ls_* final; s_pos visible to all
    if (tid == 0) { ls_part[b * CBX + bx] = ls_sum; lc_part[b * CBX + bx] = ls_cnt; }

    // ---- conf: 4 row-groups of 64, direct global loads, no barriers ----
    const int c0 = h * 20 + (h > 0 ? 1 : 0);
    const int nc = (h == 0) ? 21 : 20;

    for (int t = 0; t < 4; ++t) {
        const int rib = t * 64 + r;            // row index within block
        const int row = blockRow0 + rib;
        if (row < NN) {
            const size_t gbase = ((size_t)b * NN + row) * CC;
            const float* __restrict__ rp = pred_conf + gbase + c0;

            float v[21];
            #pragma unroll
            for (int j = 0; j < 21; ++j)
                v[j] = (j < nc) ? rp[j] : -1e30f;

            float m = v[0];
            #pragma unroll
            for (int j = 1; j < 21; ++j) m = fmaxf(m, v[j]);
            m = fmaxf(m, __shfl_xor(m, 1, 64));
            m = fmaxf(m, __shfl_xor(m, 2, 64));

            float e = 0.f;
            #pragma unroll
            for (int j = 0; j < 21; ++j) e += __expf(v[j] - m);   // pad -> exp -> 0
            e += __shfl_xor(e, 1, 64);
            e += __shfl_xor(e, 2, 64);

            const bool pos = (s_pos[rib] != 0);
            float x_sel = v[0];                // one-hot dot = v[0] for negatives
            if (pos) {
                float d = 0.f;
                #pragma unroll
                for (int j = 0; j < 21; ++j)
                    if (j < nc) d += gt_conf[gbase + c0 + j] * v[j];
                d += __shfl_xor(d, 1, 64);
                d += __shfl_xor(d, 2, 64);
                x_sel = d;                     // pred at one-hot label
            }

            const float loss = m + __logf(e) - x_sel;
            if (h == 0) {
                neg_loss[(size_t)b * NN + row] = pos ? 0.f : loss;
                if (pos) { atomicAdd(&s_cnt, 1); atomicAdd(&s_sum, loss); }
            }
        }
    }

    __syncthreads();                           // all s_cnt/s_sum atomics done
    if (tid == 0) {
        np_part[b * CBX + bx] = s_cnt;         // unconditional: no zero-init needed
        ps_part[b * CBX + bx] = s_sum;
    }
}

// ---------------- per-batch radix select + finalize (atomic mean) ----------------
// 1024 threads: scan iterations per radix pass 35 -> 9. (validated round 4)
__global__ __launch_bounds__(1024) void select_kernel(
        const float* __restrict__ neg_loss,
        const int*   __restrict__ np_part,
        const float* __restrict__ ps_part,
        const float* __restrict__ lc_part,
        const float* __restrict__ ls_part,
        float* __restrict__ out) {
    const int b    = blockIdx.x;
    const int tid  = threadIdx.x;
    const int lane = tid & 63;
    const int wv   = tid >> 6;           // 0..15
    __shared__ unsigned vals[NN];        // 34928 B
    __shared__ unsigned hist[256];
    __shared__ unsigned sh_prefix, sh_r;
    __shared__ float    s_red[16];
    __shared__ int      sh_np;
    __shared__ float    sh_ps, sh_lc, sh_ls;

    // NN = 8732 = 2183 uint4 exactly -> vectorized load, no tail
    {
        const uint4* src = (const uint4*)(neg_loss + (size_t)b * NN);
        uint4* dst = (uint4*)vals;
        for (int i = tid; i < NN / 4; i += 1024) dst[i] = src[i];
    }

    // wave 0: reduce the 35 per-block partials while other waves load vals
    if (wv == 0) {
        int   np = (lane < CBX) ? np_part[b * CBX + lane] : 0;
        float ps = (lane < CBX) ? ps_part[b * CBX + lane] : 0.f;
        float lc = (lane < CBX) ? lc_part[b * CBX + lane] : 0.f;
        float ls = (lane < CBX) ? ls_part[b * CBX + lane] : 0.f;
        #pragma unroll
        for (int o = 32; o; o >>= 1) {
            np += __shfl_down(np, o, 64);
            ps += __shfl_down(ps, o, 64);
            lc += __shfl_down(lc, o, 64);
            ls += __shfl_down(ls, o, 64);
        }
        if (lane == 0) {
            sh_np = np; sh_ps = ps; sh_lc = lc; sh_ls = ls;
            sh_prefix = 0u;
            sh_r = (unsigned)min(3 * np, NN - 1);   // clip(int(num_neg), 0, N-1)
        }
    }
    __syncthreads();

    unsigned prefix_mask = 0u;
    for (int p = 3; p >= 0; --p) {
        const unsigned pref = sh_prefix;
        const unsigned r    = sh_r;
        if (tid < 256) hist[tid] = 0u;
        __syncthreads();

        // ballot-aggregated histogram: one atomic per distinct bin per wave
        for (int i0 = 0; i0 < NN; i0 += 1024) {
            const int i = i0 + tid;
            const bool act = (i < NN) && ((vals[i] & prefix_mask) == pref);
            const unsigned v   = act ? vals[i] : 0u;
            const unsigned bin = (v >> (8 * p)) & 255u;
            unsigned long long mm = __ballot(act);
            #pragma unroll
            for (int bit = 0; bit < 8; ++bit) {
                unsigned long long s = __ballot(act && ((bin >> bit) & 1u));
                mm &= ((bin >> bit) & 1u) ? s : ~s;
            }
            if (act && ((mm & ((1ull << lane) - 1ull)) == 0ull))
                atomicAdd(&hist[bin], (unsigned)__popcll(mm));
        }
        __syncthreads();

        // wave-0 suffix scan over 256 bins (4 bins/lane) + bin pick
        if (tid < 64) {
            const unsigned h0 = hist[4 * tid + 0];
            const unsigned h1 = hist[4 * tid + 1];
            const unsigned h2 = hist[4 * tid + 2];
            const unsigned h3 = hist[4 * tid + 3];
            unsigned T = h0 + h1 + h2 + h3;
            #pragma unroll
            for (int off = 1; off < 64; off <<= 1) {
                unsigned t2 = __shfl_down(T, off, 64);
                if (tid + off < 64) T += t2;
            }
            unsigned Tn = __shfl_down(T, 1, 64);
            if (tid == 63) Tn = 0u;
            const unsigned S4 = Tn, S3 = S4 + h3, S2 = S3 + h2, S1 = S2 + h1, S0 = S1 + h0;
            int bin = -1; unsigned Slo = 0u;
            if      (S1 <= r && r < S0) { bin = 4 * tid + 0; Slo = S1; }
            else if (S2 <= r && r < S1) { bin = 4 * tid + 1; Slo = S2; }
            else if (S3 <= r && r < S2) { bin = 4 * tid + 2; Slo = S3; }
            else if (S4 <= r && r < S3) { bin = 4 * tid + 3; Slo = S4; }
            if (bin >= 0) {
                sh_r = r - Slo;
                sh_prefix = pref | ((unsigned)bin << (8 * p));
            }
        }
        __syncthreads();
        prefix_mask |= 0xFFu << (8 * p);
    }

    const float thresh = __uint_as_float(sh_prefix);   // exact (k+1)-th largest
    float s = 0.f;
    for (int i = tid; i < NN; i += 1024) {
        float v = __uint_as_float(vals[i]);
        if (v > thresh) s += v;                        // strict >, matches reference
    }
    #pragma unroll
    for (int o = 32; o; o >>= 1) s += __shfl_down(s, o, 64);
    if (lane == 0) s_red[wv] = s;
    __syncthreads();
    if (tid == 0) {
        float neg_sum = 0.f;
        #pragma unroll
        for (int w = 0; w < 16; ++w) neg_sum += s_red[w];
        float npf = (float)sh_np;
        float res = sh_ps / npf + neg_sum / (3.0f * npf) + sh_ls / sh_lc;
        atomicAdd(out, res * (1.0f / BB));
    }
}

extern "C" void kernel_launch(void* const* d_in, const int* in_sizes, int n_in,
                              void* d_out, int out_size, void* d_ws, size_t ws_size,
                              hipStream_t stream) {
    const float* pred_conf = (const float*)d_in[0];
    const float* pred_loc  = (const float*)d_in[1];
    const float* gt_conf   = (const float*)d_in[2];
    const float* gt_loc    = (const float*)d_in[3];

    float* neg     = (float*)d_ws;                  // B*N floats
    int*   np_part = (int*)(neg + (size_t)BB * NN); // [BB][CBX]
    float* ps_part = (float*)(np_part + BB * CBX);
    float* lc_part = ps_part + BB * CBX;
    float* ls_part = lc_part + BB * CBX;

    dim3 fgrid(CBX, BB);                            // 35 x 64
    fused_kernel<<<fgrid, 256, 0, stream>>>(pred_conf, gt_conf, pred_loc, gt_loc,
                                            neg, np_part, ps_part, lc_part, ls_part,
                                            (float*)d_out);

    select_kernel<<<BB, 1024, 0, stream>>>(neg, np_part, ps_part, lc_part, ls_part,
                                           (float*)d_out);
}